// Round 12
// baseline (161.318 us; speedup 1.0000x reference)
//
#include <hip/hip_runtime.h>
#include <hip/hip_bf16.h>

#define N_NODES 10000
#define NE 160000
#define CAP 96              // direct bucket capacity per (slot,node)
#define SQRT_C 0.1f
#define CC 0.01f
#define EPS 1e-15f
#define MAXNORM ((1.0f - 4e-3f) / SQRT_C)   // geoopt projx boundary, 9.96

// dual-dtype load: harness may hand float arrays as bf16 or float32; each
// needing block sniffs the dtype from emb's first 64 words (L2-hot).
__device__ __forceinline__ float ldf(const void* p, int i, int isbf) {
    return isbf ? __bfloat162float(((const __hip_bfloat16*)p)[i])
                : ((const float*)p)[i];
}

// bf16 data -> low half of word is a bf16 of N(0,1): exponent in [116,133]
// p~0.999; f32 data -> low half is uniform mantissa bits: p~0.07.
__device__ __forceinline__ int sniff_wave(const void* emb, int tid) {
    unsigned wv = ((const unsigned*)emb)[tid & 63];
    unsigned ex = (wv >> 7) & 0xFFu;
    unsigned long long m = __ballot(ex >= 116u && ex <= 133u);
    return (__popcll(m) >= 32) ? 1 : 0;
}

// ---------- wave-wide helpers (wave64) ----------
__device__ __forceinline__ float wsum(float v) {
#pragma unroll
    for (int off = 32; off > 0; off >>= 1) v += __shfl_xor(v, off, 64);
    return v;
}
__device__ __forceinline__ float wmax(float v) {
#pragma unroll
    for (int off = 32; off > 0; off >>= 1) v = fmaxf(v, __shfl_xor(v, off, 64));
    return v;
}

// only graphs 3 (b=0) and 7 (b=1) reach the output (last-timestep slice)
#define EDGE_PREAMBLE(T)                                                  \
    int slot = ((T) >= NE) ? 1 : 0;                                       \
    int e = (T) - slot * NE;                                              \
    int g = slot ? 7 : 3;

// ---------- kernel 1: node features + direct-bucket scatter + weights ----------
// (verified R11, unchanged)
__global__ __launch_bounds__(256) void pre_scatter(const void* __restrict__ emb,
                                                   const void* __restrict__ att_i,
                                                   const void* __restrict__ att_j,
                                                   const void* __restrict__ w1g,
                                                   const void* __restrict__ b1g,
                                                   const void* __restrict__ w2g,
                                                   const void* __restrict__ b2g,
                                                   const int* __restrict__ ei,
                                                   float* __restrict__ xt,
                                                   float* __restrict__ ai,
                                                   float* __restrict__ aj,
                                                   int* __restrict__ cnt,
                                                   unsigned short* __restrict__ bucket,
                                                   int* __restrict__ ovf_cnt,
                                                   unsigned* __restrict__ ovf,
                                                   int* __restrict__ flag,
                                                   float* __restrict__ wf1t,
                                                   float* __restrict__ wf2t,
                                                   float* __restrict__ hb1f,
                                                   float* __restrict__ hb2f,
                                                   float* __restrict__ hbn2) {
    __shared__ int sflag;
    int tid = threadIdx.x;
    int w = tid >> 6, lane = tid & 63;
    if (blockIdx.x < 2500) {
        if (tid < 64) { int s = sniff_wave(emb, tid); if (tid == 0) sflag = s; }
        __syncthreads();
        int isbf = sflag;
        int t = blockIdx.x * 256 + tid;            // 10000*64 threads exact
        int node = t >> 6;
        float u = ldf(emb, node * 64 + lane, isbf);
        // xt = logmap0(projx(expmap0(u))): one wsum, then analytic norms
        float n = fmaxf(sqrtf(wsum(u * u)), EPS);
        float th = tanhf(SQRT_C * n);
        float x0 = th / (SQRT_C * n) * u;
        float x0n = th / SQRT_C;
        if (x0n > MAXNORM) { x0 *= MAXNORM / x0n; x0n = MAXNORM; }
        float tc = fminf(SQRT_C * x0n, 1.0f - 1e-7f);
        float xv = atanhf(tc) / (SQRT_C * x0n) * x0;
        xt[node * 64 + lane] = xv;
        float pi = xv * ldf(att_i, lane, isbf);
        float pj = xv * ldf(att_j, lane, isbf);
#pragma unroll
        for (int off = 8; off > 0; off >>= 1) {    // aligned 16-lane head groups
            pi += __shfl_xor(pi, off, 64);
            pj += __shfl_xor(pj, off, 64);
        }
        if ((lane & 15) == 0) {
            ai[node * 4 + (lane >> 4)] = pi;
            aj[node * 4 + (lane >> 4)] = pj;
        }
    } else if (blockIdx.x < 3750) {
        int t = (blockIdx.x - 2500) * 256 + tid;   // 2*NE exact
        EDGE_PREAMBLE(t);
        int src = ei[g * 2 * NE + e];
        int dst = ei[g * 2 * NE + NE + e];
        int i = slot * N_NODES + src;
        int pos = atomicAdd(&cnt[i], 1);
        if (pos < CAP) bucket[i * CAP + pos] = (unsigned short)dst;
        else {
            int oi = atomicAdd(ovf_cnt, 1);        // astronomically rare (deg>96)
            ovf[oi] = ((unsigned)slot << 28) | ((unsigned)src << 14) | (unsigned)dst;
        }
    } else {
        if (tid < 64) { int s = sniff_wave(emb, tid); if (tid == 0) sflag = s; }
        __syncthreads();
        int isbf = sflag;
        if (tid == 0) *flag = isbf;                // publish for agg_final
        for (int i = tid; i < 1024; i += 256) {    // w1[o][c] -> wf1t[c*64+o]
            int o = i >> 4, c = i & 15;
            wf1t[c * 64 + o] = ldf(w1g, i, isbf);
        }
        for (int i = tid; i < 4096; i += 256) {    // w2[o][c] -> wf2t[c*64+o]
            int o = i >> 6, c = i & 63;
            wf2t[c * 64 + o] = ldf(w2g, i, isbf);
        }
        if (w < 2) {                               // hb = projx(expmap0(b)), + norm^2
            const void* bg = w ? b2g : b1g;
            float b = ldf(bg, lane, isbf);
            float n = fmaxf(sqrtf(wsum(b * b)), EPS);
            float th = tanhf(SQRT_C * n);
            float hv = th / (SQRT_C * n) * b;
            float hn = th / SQRT_C;
            if (hn > MAXNORM) { hv *= MAXNORM / hn; hn = MAXNORM; }
            (w ? hb2f : hb1f)[lane] = hv;
            if (lane == 0) hbn2[w] = hn * hn;
        }
    }
}

// ---------- kernel 2: MERGED aggregation + hyperbolic head ----------
// block = 1024 thr = 16 waves, owns 64 nodes [base, base+64).
// Step 1: wave w aggregates nodes base+4w..+3 (R11 node_agg body), sup -> LDS.
// Step 2: waves 0-3 run the R7 final-stage body from LDS; waves 4-15 retire.
// Zero cross-block dependencies -> no grid sync needed.
__global__ __launch_bounds__(1024, 1) void agg_final(const int* __restrict__ cnt,
                                                     const unsigned short* __restrict__ bucket,
                                                     const int* __restrict__ ovf_cnt,
                                                     const unsigned* __restrict__ ovf,
                                                     const float* __restrict__ ai,
                                                     const float* __restrict__ aj,
                                                     const float* __restrict__ xt,
                                                     const float* __restrict__ wf1t,
                                                     const float* __restrict__ wf2t,
                                                     const float* __restrict__ hb1f,
                                                     const float* __restrict__ hb2f,
                                                     const float* __restrict__ hbn2,
                                                     const int* __restrict__ flag,
                                                     void* __restrict__ outv) {
    __shared__ float arena[5184];          // step1: wlds[16][256]+dlds[16][64]
                                           // step2: Z[65*64]+pA[2][4][64]+pB[...]
    __shared__ float sups[64 * 17];        // stride 17: conflict-free both ways
    int tid = threadIdx.x;
    int w16 = tid >> 6, lane = tid & 63;
    int base = blockIdx.x * 64;            // grid: 313 blocks

    // ================= step 1: aggregation, 4 nodes per wave =================
    float* wlds = &arena[w16 * 256];
    int* dlds = (int*)&arena[4096] + w16 * 64;
    int hh = lane >> 4;
#pragma unroll 1
    for (int r = 0; r < 4; ++r) {
        int nl = w16 * 4 + r;              // local node id in [0,64)
        int idx = base + nl;
        if (idx >= 2 * N_NODES) break;
        int slot = (idx >= N_NODES) ? 1 : 0;
        int n = idx - slot * N_NODES;
        int deg = cnt[idx];
        int start = idx * CAP;

        float4 ai4 = *(const float4*)&ai[n * 4];
        float4 aj4n = *(const float4*)&aj[n * 4];
        float ain[4] = {ai4.x, ai4.y, ai4.z, ai4.w};
        float ajn[4] = {aj4n.x, aj4n.y, aj4n.z, aj4n.w};
        float acc;

        if (deg <= 63) {
            bool act = (lane <= deg);      // lane==deg is the self-loop
            int d = (lane < deg) ? (int)bucket[start + lane] : n;
            float4 a4 = act ? *(const float4*)&aj[d * 4] : make_float4(0.f, 0.f, 0.f, 0.f);
            float ajv[4] = {a4.x, a4.y, a4.z, a4.w};
            float eh[4];
#pragma unroll
            for (int h = 0; h < 4; ++h) {
                float a = ain[h] + ajv[h];
                a = (a < 0.0f) ? 0.2f * a : a;
                eh[h] = act ? expf(a) : 0.0f;  // no max-shift needed (bounds)
            }
            float sh[4];
#pragma unroll
            for (int h = 0; h < 4; ++h) sh[h] = wsum(eh[h]);
#pragma unroll
            for (int h = 0; h < 4; ++h)
                wlds[lane * 4 + h] = eh[h] * (0.25f / (sh[h] + 1e-16f));
            dlds[lane] = d;
            int m = deg + 1;
            float a0 = 0.f, a1 = 0.f, a2 = 0.f, a3 = 0.f;
            int e = 0;
            for (; e + 4 <= m; e += 4) {
                int d0 = dlds[e], d1 = dlds[e + 1];
                int d2 = dlds[e + 2], d3 = dlds[e + 3];
                float w0 = wlds[(e + 0) * 4 + hh], w1 = wlds[(e + 1) * 4 + hh];
                float w2 = wlds[(e + 2) * 4 + hh], w3 = wlds[(e + 3) * 4 + hh];
                a0 = fmaf(w0, xt[d0 * 64 + lane], a0);
                a1 = fmaf(w1, xt[d1 * 64 + lane], a1);
                a2 = fmaf(w2, xt[d2 * 64 + lane], a2);
                a3 = fmaf(w3, xt[d3 * 64 + lane], a3);
            }
            for (; e < m; ++e)
                a0 = fmaf(wlds[e * 4 + hh], xt[dlds[e] * 64 + lane], a0);
            acc = (a0 + a1) + (a2 + a3);
        } else {
            // slow path (rare): strided over bucket + overflow scan, max-shifted
            int bdeg = (deg < CAP) ? deg : CAP;
            int tov = (deg > CAP) ? *ovf_cnt : 0;
            float mh[4];
#pragma unroll
            for (int h = 0; h < 4; ++h) {
                float a = ain[h] + ajn[h];
                mh[h] = (a < 0.0f) ? 0.2f * a : a;
            }
            for (int e = lane; e < bdeg; e += 64) {
                int d = bucket[start + e];
#pragma unroll
                for (int h = 0; h < 4; ++h) {
                    float a = ain[h] + aj[d * 4 + h];
                    a = (a < 0.0f) ? 0.2f * a : a;
                    mh[h] = fmaxf(mh[h], a);
                }
            }
            for (int k = lane; k < tov; k += 64) {
                unsigned pe = ovf[k];
                if ((int)(pe >> 28) == slot && (int)((pe >> 14) & 0x3FFFu) == n) {
                    int d = pe & 0x3FFFu;
#pragma unroll
                    for (int h = 0; h < 4; ++h) {
                        float a = ain[h] + aj[d * 4 + h];
                        a = (a < 0.0f) ? 0.2f * a : a;
                        mh[h] = fmaxf(mh[h], a);
                    }
                }
            }
#pragma unroll
            for (int h = 0; h < 4; ++h) mh[h] = wmax(mh[h]);
            float sh[4] = {0.f, 0.f, 0.f, 0.f};
            if (lane == 0) {
#pragma unroll
                for (int h = 0; h < 4; ++h) {
                    float a = ain[h] + ajn[h];
                    a = (a < 0.0f) ? 0.2f * a : a;
                    sh[h] = expf(a - mh[h]);
                }
            }
            for (int e = lane; e < bdeg; e += 64) {
                int d = bucket[start + e];
#pragma unroll
                for (int h = 0; h < 4; ++h) {
                    float a = ain[h] + aj[d * 4 + h];
                    a = (a < 0.0f) ? 0.2f * a : a;
                    sh[h] += expf(a - mh[h]);
                }
            }
            for (int k = lane; k < tov; k += 64) {
                unsigned pe = ovf[k];
                if ((int)(pe >> 28) == slot && (int)((pe >> 14) & 0x3FFFu) == n) {
                    int d = pe & 0x3FFFu;
#pragma unroll
                    for (int h = 0; h < 4; ++h) {
                        float a = ain[h] + aj[d * 4 + h];
                        a = (a < 0.0f) ? 0.2f * a : a;
                        sh[h] += expf(a - mh[h]);
                    }
                }
            }
#pragma unroll
            for (int h = 0; h < 4; ++h) sh[h] = wsum(sh[h]);
            float scale[4];
#pragma unroll
            for (int h = 0; h < 4; ++h) scale[h] = 0.25f / (sh[h] + 1e-16f);
            float aih = ain[hh], mhh = mh[hh], sch = scale[hh];
            float aself = aih + ajn[hh];
            aself = (aself < 0.0f) ? 0.2f * aself : aself;
            acc = expf(aself - mhh) * sch * xt[n * 64 + lane];
            for (int e = 0; e < bdeg; ++e) {
                int d = bucket[start + e];
                float a = aih + aj[d * 4 + hh];
                a = (a < 0.0f) ? 0.2f * a : a;
                acc = fmaf(expf(a - mhh) * sch, xt[d * 64 + lane], acc);
            }
            for (int k = 0; k < tov; ++k) {
                unsigned pe = ovf[k];
                if ((int)(pe >> 28) == slot && (int)((pe >> 14) & 0x3FFFu) == n) {
                    int d = pe & 0x3FFFu;
                    float a = aih + aj[d * 4 + hh];
                    a = (a < 0.0f) ? 0.2f * a : a;
                    acc = fmaf(expf(a - mhh) * sch, xt[d * 64 + lane], acc);
                }
            }
        }
        acc += __shfl_xor(acc, 16, 64);    // head mean (x0.25 in scale)
        acc += __shfl_xor(acc, 32, 64);
        if (lane < 16) sups[nl * 17 + lane] = acc;
    }
    __syncthreads();                       // sups complete; arena free for reuse
    if (w16 >= 4) return;                  // waves 4-15 retire (live-wave barrier)

    // ================= step 2: hyperbolic head (4 waves, 64 nodes) ===========
    float* Z = arena;                      // z2s [c*64+node] then T [o*65+node]
    float* pA = &arena[4160];              // [2][4][64]
    float* pB = &arena[4672];              // [2][4][64]
    int w = w16;
    int nd = base + lane;
    bool valid = (nd < 2 * N_NODES);
    int isbf = *flag;
    float y2a = hbn2[0], y2b = hbn2[1];
    int ob = w * 16;                       // owned output base

    float v[16];
#pragma unroll
    for (int c = 0; c < 16; ++c) v[c] = valid ? sups[lane * 17 + c] : 0.0f;
    float n2 = 0.f;
#pragma unroll
    for (int c = 0; c < 16; ++c) n2 = fmaf(v[c], v[c], n2);
    float n = fmaxf(sqrtf(n2), EPS);
    float th0 = tanhf(SQRT_C * n);
    float s0 = th0 / (SQRT_C * n);
    float x0n = th0 / SQRT_C;
    if (x0n > MAXNORM) { s0 *= MAXNORM / x0n; x0n = MAXNORM; }
#pragma unroll
    for (int c = 0; c < 16; ++c) v[c] *= s0;

    float a1[16];
#pragma unroll
    for (int oj = 0; oj < 16; ++oj) a1[oj] = 0.f;
#pragma unroll
    for (int c = 0; c < 16; ++c) {
        float vc = v[c];
#pragma unroll
        for (int oj = 0; oj < 16; ++oj)
            a1[oj] = fmaf(wf1t[c * 64 + ob + oj], vc, a1[oj]);
    }
    float pn = 0.f, ph = 0.f;
#pragma unroll
    for (int oj = 0; oj < 16; ++oj) {
        pn = fmaf(a1[oj], a1[oj], pn);
        ph = fmaf(a1[oj], hb1f[ob + oj], ph);
    }
    pA[0 * 256 + w * 64 + lane] = pn; pA[1 * 256 + w * 64 + lane] = ph;
    __syncthreads();
    float mxn2 = pA[0 * 256 + lane] + pA[0 * 256 + 64 + lane] +
                 pA[0 * 256 + 128 + lane] + pA[0 * 256 + 192 + lane];
    float mxhb = pA[1 * 256 + lane] + pA[1 * 256 + 64 + lane] +
                 pA[1 * 256 + 128 + lane] + pA[1 * 256 + 192 + lane];

    float z2n;
    {
        float xn = fmaxf(x0n, EPS);
        float mxn = fmaxf(sqrtf(mxn2), EPS);
        float t = fminf(SQRT_C * xn, 1.0f - 1e-7f);
        float th = tanhf(mxn / xn * atanhf(t));
        float rs = th / (mxn * SQRT_C);
        float rn = th / SQRT_C;
        if (mxn2 == 0.0f) { rs = 0.f; rn = 0.f; }      // all(mx==0) guard
        if (rn > MAXNORM) { rs *= MAXNORM / rn; rn = MAXNORM; }
        float xy = rs * mxhb;
        float x2 = rn * rn;
        float A = 1.0f + 2.0f * CC * xy + CC * y2a;
        float B = 1.0f - CC * x2;
        float rden = 1.0f / fmaxf(1.0f + 2.0f * CC * xy + CC * CC * x2 * y2a, EPS);
        float pz = 0.f;
#pragma unroll
        for (int oj = 0; oj < 16; ++oj) {
            float z = (A * rs * a1[oj] + B * hb1f[ob + oj]) * rden;
            a1[oj] = z;
            pz = fmaf(z, z, pz);
        }
        pB[w * 64 + lane] = pz;
        __syncthreads();
        float zn2 = pB[lane] + pB[64 + lane] + pB[128 + lane] + pB[192 + lane];
        float zn = fmaxf(sqrtf(zn2), EPS);
        float sc = (zn > MAXNORM) ? MAXNORM / zn : 1.0f;
        float z1n = fminf(zn, MAXNORM);
        float lg = atanhf(fminf(SQRT_C * z1n, 1.0f - 1e-7f)) / (SQRT_C * z1n) * sc;
        float pu = 0.f;
#pragma unroll
        for (int oj = 0; oj < 16; ++oj) {
            float u = lg * a1[oj];
            u = u / (1.0f + expf(-u));
            a1[oj] = u;
            pu = fmaf(u, u, pu);
        }
        pA[w * 64 + lane] = pu;
        __syncthreads();
        float un2 = pA[lane] + pA[64 + lane] + pA[128 + lane] + pA[192 + lane];
        float un = fmaxf(sqrtf(un2), EPS);
        float th2 = tanhf(SQRT_C * un);
        float s2 = th2 / (SQRT_C * un);
        z2n = th2 / SQRT_C;
        if (z2n > MAXNORM) { s2 *= MAXNORM / z2n; z2n = MAXNORM; }
#pragma unroll
        for (int oj = 0; oj < 16; ++oj) Z[(ob + oj) * 64 + lane] = a1[oj] * s2;
        // HypDropout eval round-trip == identity (no clip possible) -> skip
    }
    __syncthreads();

    float a2[16];
#pragma unroll
    for (int oj = 0; oj < 16; ++oj) a2[oj] = 0.f;
#pragma unroll 4
    for (int c = 0; c < 64; ++c) {
        float zc = Z[c * 64 + lane];
#pragma unroll
        for (int oj = 0; oj < 16; ++oj)
            a2[oj] = fmaf(wf2t[c * 64 + ob + oj], zc, a2[oj]);
    }
    float pn2 = 0.f, ph2 = 0.f;
#pragma unroll
    for (int oj = 0; oj < 16; ++oj) {
        pn2 = fmaf(a2[oj], a2[oj], pn2);
        ph2 = fmaf(a2[oj], hb2f[ob + oj], ph2);
    }
    pB[0 * 256 + w * 64 + lane] = pn2; pB[1 * 256 + w * 64 + lane] = ph2;
    __syncthreads();
    float mxn2b = pB[0 * 256 + lane] + pB[0 * 256 + 64 + lane] +
                  pB[0 * 256 + 128 + lane] + pB[0 * 256 + 192 + lane];
    float mxhb2 = pB[1 * 256 + lane] + pB[1 * 256 + 64 + lane] +
                  pB[1 * 256 + 128 + lane] + pB[1 * 256 + 192 + lane];
    {
        float xn = fmaxf(z2n, EPS);
        float mxn = fmaxf(sqrtf(mxn2b), EPS);
        float t = fminf(SQRT_C * xn, 1.0f - 1e-7f);
        float th = tanhf(mxn / xn * atanhf(t));
        float rs = th / (mxn * SQRT_C);
        float rn = th / SQRT_C;
        if (mxn2b == 0.0f) { rs = 0.f; rn = 0.f; }
        if (rn > MAXNORM) { rs *= MAXNORM / rn; rn = MAXNORM; }
        float xy = rs * mxhb2;
        float x2 = rn * rn;
        float A = 1.0f + 2.0f * CC * xy + CC * y2b;
        float B = 1.0f - CC * x2;
        float rden = 1.0f / fmaxf(1.0f + 2.0f * CC * xy + CC * CC * x2 * y2b, EPS);
        float pz = 0.f;
#pragma unroll
        for (int oj = 0; oj < 16; ++oj) {
            float z = (A * rs * a2[oj] + B * hb2f[ob + oj]) * rden;
            a2[oj] = z;
            pz = fmaf(z, z, pz);
        }
        pA[w * 64 + lane] = pz;
        __syncthreads();
        float zn2 = pA[lane] + pA[64 + lane] + pA[128 + lane] + pA[192 + lane];
        float zn = fmaxf(sqrtf(zn2), EPS);
        float s4 = (zn > MAXNORM) ? MAXNORM / zn : 1.0f;
#pragma unroll
        for (int oj = 0; oj < 16; ++oj) Z[(ob + oj) * 65 + lane] = a2[oj] * s4;
    }
    __syncthreads();

#pragma unroll 1
    for (int k = 0; k < 16; ++k) {
        int nl = w * 16 + k;
        int ng = base + nl;
        if (ng >= 2 * N_NODES) break;
        float val = Z[lane * 65 + nl];
        if (isbf) ((__hip_bfloat16*)outv)[ng * 64 + lane] = __float2bfloat16(val);
        else      ((float*)outv)[ng * 64 + lane] = val;
    }
}

extern "C" void kernel_launch(void* const* d_in, const int* in_sizes, int n_in,
                              void* d_out, int out_size, void* d_ws, size_t ws_size,
                              hipStream_t stream) {
    // setup_inputs order: history_graphs(0, unused), edge_index(1), emb(2),
    //                     att_i(3), att_j(4), w1(5), b1(6), w2(7), b2(8)
    const int* ei = (const int*)d_in[1];
    const void* emb   = d_in[2];
    const void* att_i = d_in[3];
    const void* att_j = d_in[4];
    const void* w1 = d_in[5];
    const void* b1 = d_in[6];
    const void* w2 = d_in[7];
    const void* b2 = d_in[8];

    // workspace layout (float words), ~9.4 MB total. NO OVERLAPS:
    //   bucket [20000][96] u16 = 960000 float words: 1060032 .. 2020032
    float* ws = (float*)d_ws;
    float* xt    = ws;                                // [10000][64]: 0..640000
    float* ai    = ws + 640000;                       // [10000][4]
    float* aj    = ws + 680000;                       // [10000][4]
    int* cnt     = (int*)(ws + 1040000);              // [2][10000]: ..1060000
    int* ovf_cnt = (int*)(ws + 1060000);              // 1 int (memset covers it)
    unsigned short* bucket = (unsigned short*)(ws + 1060032); // ..2020032
    unsigned* ovf = (unsigned*)(ws + 2020032);        // [320000]: ..2340032
    int* flag     = (int*)(ws + 2340032);
    float* wf1t = ws + 2340064;                       // [16][64]: ..2341088
    float* wf2t = ws + 2341088;                       // [64][64]: ..2345184
    float* hb1f = ws + 2345184;                       // [64]
    float* hb2f = ws + 2345248;                       // [64]
    float* hbn2 = ws + 2345312;                       // [2]

    // zero cnt[20000] + ovf_cnt in one 80 KB fill
    hipMemsetAsync((void*)cnt, 0, (2 * N_NODES + 8) * sizeof(int), stream);
    hipLaunchKernelGGL(pre_scatter, dim3(3751), dim3(256), 0, stream,
                       emb, att_i, att_j, w1, b1, w2, b2, ei,
                       xt, ai, aj, cnt, bucket, ovf_cnt, ovf, flag,
                       wf1t, wf2t, hb1f, hb2f, hbn2);
    hipLaunchKernelGGL(agg_final, dim3(313), dim3(1024), 0, stream,
                       cnt, bucket, ovf_cnt, ovf, ai, aj, xt,
                       wf1t, wf2t, hb1f, hb2f, hbn2, flag, d_out);
}

// Round 13
// 147.332 us; speedup vs baseline: 1.0949x; 1.0949x over previous
//
#include <hip/hip_runtime.h>
#include <hip/hip_bf16.h>

#define N_NODES 10000
#define NE 160000
#define CAP 96              // direct bucket capacity per (slot,node)
#define SQRT_C 0.1f
#define CC 0.01f
#define EPS 1e-15f
#define MAXNORM ((1.0f - 4e-3f) / SQRT_C)   // geoopt projx boundary, 9.96

// fast transcendentals (bounded, sign-known args; ~1 ulp worse than libm)
__device__ __forceinline__ float fexp(float x) { return __expf(x); }
__device__ __forceinline__ float ftanh_pos(float x) {      // x >= 0
    return 1.0f - 2.0f / (__expf(2.0f * x) + 1.0f);
}
__device__ __forceinline__ float fatanh01(float t) {       // 0 <= t < 1
    return 0.5f * __logf((1.0f + t) / (1.0f - t));
}

// dual-dtype load: harness may hand float arrays as bf16 or float32; each
// needing block sniffs the dtype from emb's first 64 words (L2-hot).
__device__ __forceinline__ float ldf(const void* p, int i, int isbf) {
    return isbf ? __bfloat162float(((const __hip_bfloat16*)p)[i])
                : ((const float*)p)[i];
}

// bf16 data -> low half of word is a bf16 of N(0,1): exponent in [116,133]
// p~0.999; f32 data -> low half is uniform mantissa bits: p~0.07.
__device__ __forceinline__ int sniff_wave(const void* emb, int tid) {
    unsigned wv = ((const unsigned*)emb)[tid & 63];
    unsigned ex = (wv >> 7) & 0xFFu;
    unsigned long long m = __ballot(ex >= 116u && ex <= 133u);
    return (__popcll(m) >= 32) ? 1 : 0;
}

// ---------- wave-wide helpers (wave64) ----------
__device__ __forceinline__ float wsum(float v) {
#pragma unroll
    for (int off = 32; off > 0; off >>= 1) v += __shfl_xor(v, off, 64);
    return v;
}
__device__ __forceinline__ float wmax(float v) {
#pragma unroll
    for (int off = 32; off > 0; off >>= 1) v = fmaxf(v, __shfl_xor(v, off, 64));
    return v;
}

// ---------- kernel 1: node features + direct-bucket scatter + weights ----------
// blocks [0,2500): wave-per-node tangent features + attention dots
// blocks [2500,3125): scatter; each thread does edge e for BOTH graphs 3 and 7
//                     (two independent atomic chains in flight)
// block 3125: weights -> fp32 transposed + hyperbolic biases + publish flag
__global__ __launch_bounds__(256) void pre_scatter(const void* __restrict__ emb,
                                                   const void* __restrict__ att_i,
                                                   const void* __restrict__ att_j,
                                                   const void* __restrict__ w1g,
                                                   const void* __restrict__ b1g,
                                                   const void* __restrict__ w2g,
                                                   const void* __restrict__ b2g,
                                                   const int* __restrict__ ei,
                                                   float* __restrict__ xt,
                                                   float* __restrict__ ai,
                                                   float* __restrict__ aj,
                                                   int* __restrict__ cnt,
                                                   unsigned short* __restrict__ bucket,
                                                   int* __restrict__ ovf_cnt,
                                                   unsigned* __restrict__ ovf,
                                                   int* __restrict__ flag,
                                                   float* __restrict__ wf1t,
                                                   float* __restrict__ wf2t,
                                                   float* __restrict__ hb1f,
                                                   float* __restrict__ hb2f,
                                                   float* __restrict__ hbn2) {
    __shared__ int sflag;
    int tid = threadIdx.x;
    int w = tid >> 6, lane = tid & 63;
    if (blockIdx.x < 2500) {
        if (tid < 64) { int s = sniff_wave(emb, tid); if (tid == 0) sflag = s; }
        __syncthreads();
        int isbf = sflag;
        int t = blockIdx.x * 256 + tid;            // 10000*64 threads exact
        int node = t >> 6;
        float u = ldf(emb, node * 64 + lane, isbf);
        // xt = logmap0(projx(expmap0(u))): one wsum, then analytic norms
        float n = fmaxf(sqrtf(wsum(u * u)), EPS);
        float th = ftanh_pos(SQRT_C * n);
        float x0 = th / (SQRT_C * n) * u;
        float x0n = th / SQRT_C;
        if (x0n > MAXNORM) { x0 *= MAXNORM / x0n; x0n = MAXNORM; }
        float tc = fminf(SQRT_C * x0n, 1.0f - 1e-7f);
        float xv = fatanh01(tc) / (SQRT_C * x0n) * x0;
        xt[node * 64 + lane] = xv;
        float pi = xv * ldf(att_i, lane, isbf);
        float pj = xv * ldf(att_j, lane, isbf);
#pragma unroll
        for (int off = 8; off > 0; off >>= 1) {    // aligned 16-lane head groups
            pi += __shfl_xor(pi, off, 64);
            pj += __shfl_xor(pj, off, 64);
        }
        if ((lane & 15) == 0) {
            ai[node * 4 + (lane >> 4)] = pi;
            aj[node * 4 + (lane >> 4)] = pj;
        }
    } else if (blockIdx.x < 3125) {
        int e = (blockIdx.x - 2500) * 256 + tid;   // [0, NE) exact (625 blocks)
        // slot 0 = graph 3, slot 1 = graph 7: independent atomics, overlapped
        int s0 = ei[3 * 2 * NE + e], d0 = ei[3 * 2 * NE + NE + e];
        int s1 = ei[7 * 2 * NE + e], d1 = ei[7 * 2 * NE + NE + e];
        int i0 = s0, i1 = N_NODES + s1;
        int p0 = atomicAdd(&cnt[i0], 1);
        int p1 = atomicAdd(&cnt[i1], 1);
        if (p0 < CAP) bucket[i0 * CAP + p0] = (unsigned short)d0;
        else {
            int oi = atomicAdd(ovf_cnt, 1);        // astronomically rare (deg>96)
            ovf[oi] = (0u << 28) | ((unsigned)s0 << 14) | (unsigned)d0;
        }
        if (p1 < CAP) bucket[i1 * CAP + p1] = (unsigned short)d1;
        else {
            int oi = atomicAdd(ovf_cnt, 1);
            ovf[oi] = (1u << 28) | ((unsigned)s1 << 14) | (unsigned)d1;
        }
    } else {
        if (tid < 64) { int s = sniff_wave(emb, tid); if (tid == 0) sflag = s; }
        __syncthreads();
        int isbf = sflag;
        if (tid == 0) *flag = isbf;                // publish for final_stage
        for (int i = tid; i < 1024; i += 256) {    // w1[o][c] -> wf1t[c*64+o]
            int o = i >> 4, c = i & 15;
            wf1t[c * 64 + o] = ldf(w1g, i, isbf);
        }
        for (int i = tid; i < 4096; i += 256) {    // w2[o][c] -> wf2t[c*64+o]
            int o = i >> 6, c = i & 63;
            wf2t[c * 64 + o] = ldf(w2g, i, isbf);
        }
        if (w < 2) {                               // hb = projx(expmap0(b)), + norm^2
            const void* bg = w ? b2g : b1g;
            float b = ldf(bg, lane, isbf);
            float n = fmaxf(sqrtf(wsum(b * b)), EPS);
            float th = ftanh_pos(SQRT_C * n);
            float hv = th / (SQRT_C * n) * b;
            float hn = th / SQRT_C;
            if (hn > MAXNORM) { hv *= MAXNORM / hn; hn = MAXNORM; }
            (w ? hb2f : hb1f)[lane] = hv;
            if (lane == 0) hbn2[w] = hn * hn;
        }
    }
}

// ---------- kernel 2: per-node softmax + aggregation, atomic-free ----------
// (verified R11 structure: 1 node per wave, 20000 waves)
__global__ __launch_bounds__(256) void node_agg(const int* __restrict__ cnt,
                                                const unsigned short* __restrict__ bucket,
                                                const int* __restrict__ ovf_cnt,
                                                const unsigned* __restrict__ ovf,
                                                const float* __restrict__ ai,
                                                const float* __restrict__ aj,
                                                const float* __restrict__ xt,
                                                float* __restrict__ sup_t) {
    __shared__ float wlds[4][64 * 4];
    __shared__ int dlds[4][64];
    int w = threadIdx.x >> 6, lane = threadIdx.x & 63;
    int idx = blockIdx.x * 4 + w;          // grid exact: 20000 waves
    int slot = (idx >= N_NODES) ? 1 : 0;
    int n = idx - slot * N_NODES;
    int deg = cnt[idx];
    int start = idx * CAP;

    float4 ai4 = *(const float4*)&ai[n * 4];
    float4 aj4n = *(const float4*)&aj[n * 4];
    float ain[4] = {ai4.x, ai4.y, ai4.z, ai4.w};
    float ajn[4] = {aj4n.x, aj4n.y, aj4n.z, aj4n.w};
    int hh = lane >> 4;
    float acc;

    if (deg <= 63) {
        bool act = (lane <= deg);          // lane==deg is the self-loop
        int d = (lane < deg) ? (int)bucket[start + lane] : n;
        float4 a4 = act ? *(const float4*)&aj[d * 4] : make_float4(0.f, 0.f, 0.f, 0.f);
        float ajv[4] = {a4.x, a4.y, a4.z, a4.w};
        float eh[4];
#pragma unroll
        for (int h = 0; h < 4; ++h) {
            float a = ain[h] + ajv[h];
            a = (a < 0.0f) ? 0.2f * a : a;
            eh[h] = act ? fexp(a) : 0.0f;  // no max-shift needed (|a|<=76 << 88)
        }
        float sh[4];
#pragma unroll
        for (int h = 0; h < 4; ++h) sh[h] = wsum(eh[h]);
#pragma unroll
        for (int h = 0; h < 4; ++h)
            wlds[w][lane * 4 + h] = eh[h] * (0.25f / (sh[h] + 1e-16f));
        dlds[w][lane] = d;
        // gather, unrolled x4 with independent accumulators (4 loads in flight)
        int m = deg + 1;
        float a0 = 0.f, a1 = 0.f, a2 = 0.f, a3 = 0.f;
        int e = 0;
        for (; e + 4 <= m; e += 4) {
            int d0 = dlds[w][e], d1 = dlds[w][e + 1];
            int d2 = dlds[w][e + 2], d3 = dlds[w][e + 3];
            float w0 = wlds[w][(e + 0) * 4 + hh], w1 = wlds[w][(e + 1) * 4 + hh];
            float w2 = wlds[w][(e + 2) * 4 + hh], w3 = wlds[w][(e + 3) * 4 + hh];
            a0 = fmaf(w0, xt[d0 * 64 + lane], a0);
            a1 = fmaf(w1, xt[d1 * 64 + lane], a1);
            a2 = fmaf(w2, xt[d2 * 64 + lane], a2);
            a3 = fmaf(w3, xt[d3 * 64 + lane], a3);
        }
        for (; e < m; ++e)
            a0 = fmaf(wlds[w][e * 4 + hh], xt[dlds[w][e] * 64 + lane], a0);
        acc = (a0 + a1) + (a2 + a3);
    } else {
        // slow path (rare): strided over bucket + overflow scan, max-shifted
        int bdeg = (deg < CAP) ? deg : CAP;
        int tov = (deg > CAP) ? *ovf_cnt : 0;
        float mh[4];
#pragma unroll
        for (int h = 0; h < 4; ++h) {
            float a = ain[h] + ajn[h];
            mh[h] = (a < 0.0f) ? 0.2f * a : a;
        }
        for (int e = lane; e < bdeg; e += 64) {
            int d = bucket[start + e];
#pragma unroll
            for (int h = 0; h < 4; ++h) {
                float a = ain[h] + aj[d * 4 + h];
                a = (a < 0.0f) ? 0.2f * a : a;
                mh[h] = fmaxf(mh[h], a);
            }
        }
        for (int k = lane; k < tov; k += 64) {
            unsigned pe = ovf[k];
            if ((int)(pe >> 28) == slot && (int)((pe >> 14) & 0x3FFFu) == n) {
                int d = pe & 0x3FFFu;
#pragma unroll
                for (int h = 0; h < 4; ++h) {
                    float a = ain[h] + aj[d * 4 + h];
                    a = (a < 0.0f) ? 0.2f * a : a;
                    mh[h] = fmaxf(mh[h], a);
                }
            }
        }
#pragma unroll
        for (int h = 0; h < 4; ++h) mh[h] = wmax(mh[h]);
        float sh[4] = {0.f, 0.f, 0.f, 0.f};
        if (lane == 0) {
#pragma unroll
            for (int h = 0; h < 4; ++h) {
                float a = ain[h] + ajn[h];
                a = (a < 0.0f) ? 0.2f * a : a;
                sh[h] = fexp(a - mh[h]);
            }
        }
        for (int e = lane; e < bdeg; e += 64) {
            int d = bucket[start + e];
#pragma unroll
            for (int h = 0; h < 4; ++h) {
                float a = ain[h] + aj[d * 4 + h];
                a = (a < 0.0f) ? 0.2f * a : a;
                sh[h] += fexp(a - mh[h]);
            }
        }
        for (int k = lane; k < tov; k += 64) {
            unsigned pe = ovf[k];
            if ((int)(pe >> 28) == slot && (int)((pe >> 14) & 0x3FFFu) == n) {
                int d = pe & 0x3FFFu;
#pragma unroll
                for (int h = 0; h < 4; ++h) {
                    float a = ain[h] + aj[d * 4 + h];
                    a = (a < 0.0f) ? 0.2f * a : a;
                    sh[h] += fexp(a - mh[h]);
                }
            }
        }
#pragma unroll
        for (int h = 0; h < 4; ++h) sh[h] = wsum(sh[h]);
        float scale[4];
#pragma unroll
        for (int h = 0; h < 4; ++h) scale[h] = 0.25f / (sh[h] + 1e-16f);
        float aih = ain[hh], mhh = mh[hh], sch = scale[hh];
        float aself = aih + ajn[hh];
        aself = (aself < 0.0f) ? 0.2f * aself : aself;
        acc = fexp(aself - mhh) * sch * xt[n * 64 + lane];
        for (int e = 0; e < bdeg; ++e) {
            int d = bucket[start + e];
            float a = aih + aj[d * 4 + hh];
            a = (a < 0.0f) ? 0.2f * a : a;
            acc = fmaf(fexp(a - mhh) * sch, xt[d * 64 + lane], acc);
        }
        for (int k = 0; k < tov; ++k) {
            unsigned pe = ovf[k];
            if ((int)(pe >> 28) == slot && (int)((pe >> 14) & 0x3FFFu) == n) {
                int d = pe & 0x3FFFu;
                float a = aih + aj[d * 4 + hh];
                a = (a < 0.0f) ? 0.2f * a : a;
                acc = fmaf(fexp(a - mhh) * sch, xt[d * 64 + lane], acc);
            }
        }
    }
    acc += __shfl_xor(acc, 16, 64);        // head mean (x0.25 in scale)
    acc += __shfl_xor(acc, 32, 64);
    if (lane < 16) sup_t[lane * 20000 + idx] = acc;
}

// ---------- kernel 3: hyperbolic head, 4-wave cooperative (verified R7/R11) ----------
__global__ __launch_bounds__(256) void final_stage(const float* __restrict__ sup_t,
                                                   const float* __restrict__ wf1t,
                                                   const float* __restrict__ wf2t,
                                                   const float* __restrict__ hb1f,
                                                   const float* __restrict__ hb2f,
                                                   const float* __restrict__ hbn2,
                                                   const int* __restrict__ flag,
                                                   void* __restrict__ outv) {
    __shared__ float Z[65 * 64];           // z2s [c*64+node] then T [o*65+node]
    __shared__ float pA[2][4][64];
    __shared__ float pB[2][4][64];
    int w = threadIdx.x >> 6, lane = threadIdx.x & 63;
    int base = blockIdx.x * 64;            // grid: 313 blocks
    int nd = base + lane;
    bool valid = (nd < 2 * N_NODES);
    int isbf = *flag;
    float y2a = hbn2[0], y2b = hbn2[1];
    int ob = w * 16;                       // owned output base

    float v[16];
#pragma unroll
    for (int c = 0; c < 16; ++c) v[c] = valid ? sup_t[c * 20000 + nd] : 0.0f;
    float n2 = 0.f;
#pragma unroll
    for (int c = 0; c < 16; ++c) n2 = fmaf(v[c], v[c], n2);
    float n = fmaxf(sqrtf(n2), EPS);
    float th0 = ftanh_pos(SQRT_C * n);
    float s0 = th0 / (SQRT_C * n);
    float x0n = th0 / SQRT_C;
    if (x0n > MAXNORM) { s0 *= MAXNORM / x0n; x0n = MAXNORM; }
#pragma unroll
    for (int c = 0; c < 16; ++c) v[c] *= s0;

    float a1[16];
#pragma unroll
    for (int oj = 0; oj < 16; ++oj) a1[oj] = 0.f;
#pragma unroll
    for (int c = 0; c < 16; ++c) {
        float vc = v[c];
#pragma unroll
        for (int oj = 0; oj < 16; ++oj)
            a1[oj] = fmaf(wf1t[c * 64 + ob + oj], vc, a1[oj]);
    }
    float pn = 0.f, ph = 0.f;
#pragma unroll
    for (int oj = 0; oj < 16; ++oj) {
        pn = fmaf(a1[oj], a1[oj], pn);
        ph = fmaf(a1[oj], hb1f[ob + oj], ph);
    }
    pA[0][w][lane] = pn; pA[1][w][lane] = ph;
    __syncthreads();
    float mxn2 = pA[0][0][lane] + pA[0][1][lane] + pA[0][2][lane] + pA[0][3][lane];
    float mxhb = pA[1][0][lane] + pA[1][1][lane] + pA[1][2][lane] + pA[1][3][lane];

    float z2n;
    {
        float xn = fmaxf(x0n, EPS);
        float mxn = fmaxf(sqrtf(mxn2), EPS);
        float t = fminf(SQRT_C * xn, 1.0f - 1e-7f);
        float th = ftanh_pos(mxn / xn * fatanh01(t));
        float rs = th / (mxn * SQRT_C);
        float rn = th / SQRT_C;
        if (mxn2 == 0.0f) { rs = 0.f; rn = 0.f; }      // all(mx==0) guard
        if (rn > MAXNORM) { rs *= MAXNORM / rn; rn = MAXNORM; }
        float xy = rs * mxhb;
        float x2 = rn * rn;
        float A = 1.0f + 2.0f * CC * xy + CC * y2a;
        float B = 1.0f - CC * x2;
        float rden = 1.0f / fmaxf(1.0f + 2.0f * CC * xy + CC * CC * x2 * y2a, EPS);
        float pz = 0.f;
#pragma unroll
        for (int oj = 0; oj < 16; ++oj) {
            float z = (A * rs * a1[oj] + B * hb1f[ob + oj]) * rden;
            a1[oj] = z;
            pz = fmaf(z, z, pz);
        }
        pB[0][w][lane] = pz;
        __syncthreads();
        float zn2 = pB[0][0][lane] + pB[0][1][lane] + pB[0][2][lane] + pB[0][3][lane];
        float zn = fmaxf(sqrtf(zn2), EPS);
        float sc = (zn > MAXNORM) ? MAXNORM / zn : 1.0f;
        float z1n = fminf(zn, MAXNORM);
        float lg = fatanh01(fminf(SQRT_C * z1n, 1.0f - 1e-7f)) / (SQRT_C * z1n) * sc;
        float pu = 0.f;
#pragma unroll
        for (int oj = 0; oj < 16; ++oj) {
            float u = lg * a1[oj];
            u = u / (1.0f + __expf(-u));
            a1[oj] = u;
            pu = fmaf(u, u, pu);
        }
        pA[0][w][lane] = pu;
        __syncthreads();
        float un2 = pA[0][0][lane] + pA[0][1][lane] + pA[0][2][lane] + pA[0][3][lane];
        float un = fmaxf(sqrtf(un2), EPS);
        float th2 = ftanh_pos(SQRT_C * un);
        float s2 = th2 / (SQRT_C * un);
        z2n = th2 / SQRT_C;
        if (z2n > MAXNORM) { s2 *= MAXNORM / z2n; z2n = MAXNORM; }
#pragma unroll
        for (int oj = 0; oj < 16; ++oj) Z[(ob + oj) * 64 + lane] = a1[oj] * s2;
        // HypDropout eval round-trip == identity (no clip possible) -> skip
    }
    __syncthreads();

    float a2[16];
#pragma unroll
    for (int oj = 0; oj < 16; ++oj) a2[oj] = 0.f;
#pragma unroll 4
    for (int c = 0; c < 64; ++c) {
        float zc = Z[c * 64 + lane];
#pragma unroll
        for (int oj = 0; oj < 16; ++oj)
            a2[oj] = fmaf(wf2t[c * 64 + ob + oj], zc, a2[oj]);
    }
    float pn2 = 0.f, ph2 = 0.f;
#pragma unroll
    for (int oj = 0; oj < 16; ++oj) {
        pn2 = fmaf(a2[oj], a2[oj], pn2);
        ph2 = fmaf(a2[oj], hb2f[ob + oj], ph2);
    }
    pB[0][w][lane] = pn2; pB[1][w][lane] = ph2;
    __syncthreads();
    float mxn2b = pB[0][0][lane] + pB[0][1][lane] + pB[0][2][lane] + pB[0][3][lane];
    float mxhb2 = pB[1][0][lane] + pB[1][1][lane] + pB[1][2][lane] + pB[1][3][lane];
    {
        float xn = fmaxf(z2n, EPS);
        float mxn = fmaxf(sqrtf(mxn2b), EPS);
        float t = fminf(SQRT_C * xn, 1.0f - 1e-7f);
        float th = ftanh_pos(mxn / xn * fatanh01(t));
        float rs = th / (mxn * SQRT_C);
        float rn = th / SQRT_C;
        if (mxn2b == 0.0f) { rs = 0.f; rn = 0.f; }
        if (rn > MAXNORM) { rs *= MAXNORM / rn; rn = MAXNORM; }
        float xy = rs * mxhb2;
        float x2 = rn * rn;
        float A = 1.0f + 2.0f * CC * xy + CC * y2b;
        float B = 1.0f - CC * x2;
        float rden = 1.0f / fmaxf(1.0f + 2.0f * CC * xy + CC * CC * x2 * y2b, EPS);
        float pz = 0.f;
#pragma unroll
        for (int oj = 0; oj < 16; ++oj) {
            float z = (A * rs * a2[oj] + B * hb2f[ob + oj]) * rden;
            a2[oj] = z;
            pz = fmaf(z, z, pz);
        }
        pA[0][w][lane] = pz;
        __syncthreads();
        float zn2 = pA[0][0][lane] + pA[0][1][lane] + pA[0][2][lane] + pA[0][3][lane];
        float zn = fmaxf(sqrtf(zn2), EPS);
        float s4 = (zn > MAXNORM) ? MAXNORM / zn : 1.0f;
#pragma unroll
        for (int oj = 0; oj < 16; ++oj) Z[(ob + oj) * 65 + lane] = a2[oj] * s4;
    }
    __syncthreads();

#pragma unroll 1
    for (int k = 0; k < 16; ++k) {
        int nl = w * 16 + k;
        int ng = base + nl;
        if (ng >= 2 * N_NODES) break;
        float val = Z[lane * 65 + nl];
        if (isbf) ((__hip_bfloat16*)outv)[ng * 64 + lane] = __float2bfloat16(val);
        else      ((float*)outv)[ng * 64 + lane] = val;
    }
}

extern "C" void kernel_launch(void* const* d_in, const int* in_sizes, int n_in,
                              void* d_out, int out_size, void* d_ws, size_t ws_size,
                              hipStream_t stream) {
    // setup_inputs order: history_graphs(0, unused), edge_index(1), emb(2),
    //                     att_i(3), att_j(4), w1(5), b1(6), w2(7), b2(8)
    const int* ei = (const int*)d_in[1];
    const void* emb   = d_in[2];
    const void* att_i = d_in[3];
    const void* att_j = d_in[4];
    const void* w1 = d_in[5];
    const void* b1 = d_in[6];
    const void* w2 = d_in[7];
    const void* b2 = d_in[8];

    // workspace layout (float words), ~9.4 MB total. NO OVERLAPS (R11-verified):
    //   bucket [20000][96] u16 = 960000 float words: 1060032 .. 2020032
    float* ws = (float*)d_ws;
    float* xt    = ws;                                // [10000][64]: 0..640000
    float* ai    = ws + 640000;                       // [10000][4]
    float* aj    = ws + 680000;                       // [10000][4]
    float* sup_t = ws + 720000;                       // [16][20000]: ..1040000
    int* cnt     = (int*)(ws + 1040000);              // [2][10000]: ..1060000
    int* ovf_cnt = (int*)(ws + 1060000);              // 1 int (memset covers it)
    unsigned short* bucket = (unsigned short*)(ws + 1060032); // ..2020032
    unsigned* ovf = (unsigned*)(ws + 2020032);        // [320000]: ..2340032
    int* flag     = (int*)(ws + 2340032);
    float* wf1t = ws + 2340064;                       // [16][64]: ..2341088
    float* wf2t = ws + 2341088;                       // [64][64]: ..2345184
    float* hb1f = ws + 2345184;                       // [64]
    float* hb2f = ws + 2345248;                       // [64]
    float* hbn2 = ws + 2345312;                       // [2]

    // zero cnt[20000] + ovf_cnt in one 80 KB fill
    hipMemsetAsync((void*)cnt, 0, (2 * N_NODES + 8) * sizeof(int), stream);
    hipLaunchKernelGGL(pre_scatter, dim3(3126), dim3(256), 0, stream,
                       emb, att_i, att_j, w1, b1, w2, b2, ei,
                       xt, ai, aj, cnt, bucket, ovf_cnt, ovf, flag,
                       wf1t, wf2t, hb1f, hb2f, hbn2);
    hipLaunchKernelGGL(node_agg, dim3(5000), dim3(256), 0, stream,
                       cnt, bucket, ovf_cnt, ovf, ai, aj, xt, sup_t);
    hipLaunchKernelGGL(final_stage, dim3(313), dim3(256), 0, stream,
                       sup_t, wf1t, wf2t, hb1f, hb2f, hbn2, flag, d_out);
}

// Round 14
// 143.584 us; speedup vs baseline: 1.1235x; 1.0261x over previous
//
#include <hip/hip_runtime.h>
#include <hip/hip_bf16.h>

#define N_NODES 10000
#define NE 160000
#define CAP 96              // direct bucket capacity per (slot,node)
#define SQRT_C 0.1f
#define CC 0.01f
#define EPS 1e-15f
#define MAXNORM ((1.0f - 4e-3f) / SQRT_C)   // geoopt projx boundary, 9.96

// fast transcendentals (bounded, sign-known args; ~1 ulp worse than libm)
__device__ __forceinline__ float fexp(float x) { return __expf(x); }
__device__ __forceinline__ float ftanh_pos(float x) {      // x >= 0
    return 1.0f - 2.0f / (__expf(2.0f * x) + 1.0f);
}
__device__ __forceinline__ float fatanh01(float t) {       // 0 <= t < 1
    return 0.5f * __logf((1.0f + t) / (1.0f - t));
}

// dual-dtype load: harness may hand float arrays as bf16 or float32; each
// needing block sniffs the dtype from emb's first 64 words (L2-hot).
__device__ __forceinline__ float ldf(const void* p, int i, int isbf) {
    return isbf ? __bfloat162float(((const __hip_bfloat16*)p)[i])
                : ((const float*)p)[i];
}

// bf16 data -> low half of word is a bf16 of N(0,1): exponent in [116,133]
// p~0.999; f32 data -> low half is uniform mantissa bits: p~0.07.
__device__ __forceinline__ int sniff_wave(const void* emb, int tid) {
    unsigned wv = ((const unsigned*)emb)[tid & 63];
    unsigned ex = (wv >> 7) & 0xFFu;
    unsigned long long m = __ballot(ex >= 116u && ex <= 133u);
    return (__popcll(m) >= 32) ? 1 : 0;
}

// ---------- wave-wide helpers (wave64) ----------
__device__ __forceinline__ float wsum(float v) {
#pragma unroll
    for (int off = 32; off > 0; off >>= 1) v += __shfl_xor(v, off, 64);
    return v;
}
__device__ __forceinline__ float wmax(float v) {
#pragma unroll
    for (int off = 32; off > 0; off >>= 1) v = fmaxf(v, __shfl_xor(v, off, 64));
    return v;
}

// ---------- kernel 1: node features + direct-bucket scatter + weights ----------
// blocks [0,2500): wave-per-node tangent features + attention dots
// blocks [2500,2813): scatter; each thread does 2 edges x 2 graphs
//                     (4 independent atomic chains in flight)
// block 2813: weights -> fp32 transposed + hyperbolic biases + publish flag
__global__ __launch_bounds__(256) void pre_scatter(const void* __restrict__ emb,
                                                   const void* __restrict__ att_i,
                                                   const void* __restrict__ att_j,
                                                   const void* __restrict__ w1g,
                                                   const void* __restrict__ b1g,
                                                   const void* __restrict__ w2g,
                                                   const void* __restrict__ b2g,
                                                   const int* __restrict__ ei,
                                                   float* __restrict__ xt,
                                                   float* __restrict__ ai,
                                                   float* __restrict__ aj,
                                                   int* __restrict__ cnt,
                                                   unsigned short* __restrict__ bucket,
                                                   int* __restrict__ ovf_cnt,
                                                   unsigned* __restrict__ ovf,
                                                   int* __restrict__ flag,
                                                   float* __restrict__ wf1t,
                                                   float* __restrict__ wf2t,
                                                   float* __restrict__ hb1f,
                                                   float* __restrict__ hb2f,
                                                   float* __restrict__ hbn2) {
    __shared__ int sflag;
    int tid = threadIdx.x;
    int w = tid >> 6, lane = tid & 63;
    if (blockIdx.x < 2500) {
        if (tid < 64) { int s = sniff_wave(emb, tid); if (tid == 0) sflag = s; }
        __syncthreads();
        int isbf = sflag;
        int t = blockIdx.x * 256 + tid;            // 10000*64 threads exact
        int node = t >> 6;
        float u = ldf(emb, node * 64 + lane, isbf);
        // xt = logmap0(projx(expmap0(u))): one wsum, then analytic norms
        float n = fmaxf(sqrtf(wsum(u * u)), EPS);
        float th = ftanh_pos(SQRT_C * n);
        float x0 = th / (SQRT_C * n) * u;
        float x0n = th / SQRT_C;
        if (x0n > MAXNORM) { x0 *= MAXNORM / x0n; x0n = MAXNORM; }
        float tc = fminf(SQRT_C * x0n, 1.0f - 1e-7f);
        float xv = fatanh01(tc) / (SQRT_C * x0n) * x0;
        xt[node * 64 + lane] = xv;
        float pi = xv * ldf(att_i, lane, isbf);
        float pj = xv * ldf(att_j, lane, isbf);
#pragma unroll
        for (int off = 8; off > 0; off >>= 1) {    // aligned 16-lane head groups
            pi += __shfl_xor(pi, off, 64);
            pj += __shfl_xor(pj, off, 64);
        }
        if ((lane & 15) == 0) {
            ai[node * 4 + (lane >> 4)] = pi;
            aj[node * 4 + (lane >> 4)] = pj;
        }
    } else if (blockIdx.x < 2813) {
        int e0 = (blockIdx.x - 2500) * 512 + tid;  // 313 blocks x 512 edges
#pragma unroll
        for (int q = 0; q < 2; ++q) {
            int e = e0 + q * 256;
            if (e >= NE) break;
            // slot 0 = graph 3, slot 1 = graph 7: independent atomic chains
            int s0 = ei[3 * 2 * NE + e], d0 = ei[3 * 2 * NE + NE + e];
            int s1 = ei[7 * 2 * NE + e], d1 = ei[7 * 2 * NE + NE + e];
            int i0 = s0, i1 = N_NODES + s1;
            int p0 = atomicAdd(&cnt[i0], 1);
            int p1 = atomicAdd(&cnt[i1], 1);
            if (p0 < CAP) bucket[i0 * CAP + p0] = (unsigned short)d0;
            else {
                int oi = atomicAdd(ovf_cnt, 1);    // astronomically rare (deg>96)
                ovf[oi] = (0u << 28) | ((unsigned)s0 << 14) | (unsigned)d0;
            }
            if (p1 < CAP) bucket[i1 * CAP + p1] = (unsigned short)d1;
            else {
                int oi = atomicAdd(ovf_cnt, 1);
                ovf[oi] = (1u << 28) | ((unsigned)s1 << 14) | (unsigned)d1;
            }
        }
    } else {
        if (tid < 64) { int s = sniff_wave(emb, tid); if (tid == 0) sflag = s; }
        __syncthreads();
        int isbf = sflag;
        if (tid == 0) *flag = isbf;                // publish for final_stage
        for (int i = tid; i < 1024; i += 256) {    // w1[o][c] -> wf1t[c*64+o]
            int o = i >> 4, c = i & 15;
            wf1t[c * 64 + o] = ldf(w1g, i, isbf);
        }
        for (int i = tid; i < 4096; i += 256) {    // w2[o][c] -> wf2t[c*64+o]
            int o = i >> 6, c = i & 63;
            wf2t[c * 64 + o] = ldf(w2g, i, isbf);
        }
        if (w < 2) {                               // hb = projx(expmap0(b)), + norm^2
            const void* bg = w ? b2g : b1g;
            float b = ldf(bg, lane, isbf);
            float n = fmaxf(sqrtf(wsum(b * b)), EPS);
            float th = ftanh_pos(SQRT_C * n);
            float hv = th / (SQRT_C * n) * b;
            float hn = th / SQRT_C;
            if (hn > MAXNORM) { hv *= MAXNORM / hn; hn = MAXNORM; }
            (w ? hb2f : hb1f)[lane] = hv;
            if (lane == 0) hbn2[w] = hn * hn;
        }
    }
}

// ---------- kernel 2: per-node softmax + aggregation, atomic-free ----------
// fast path (deg<=63): edge-per-lane, no max-shift (|alpha| bounded << 88),
// weights staged in LDS, gather unrolled x8 (8 L2 loads in flight).
__global__ __launch_bounds__(256) void node_agg(const int* __restrict__ cnt,
                                                const unsigned short* __restrict__ bucket,
                                                const int* __restrict__ ovf_cnt,
                                                const unsigned* __restrict__ ovf,
                                                const float* __restrict__ ai,
                                                const float* __restrict__ aj,
                                                const float* __restrict__ xt,
                                                float* __restrict__ sup_t) {
    __shared__ float wlds[4][64 * 4];
    __shared__ int dlds[4][64];
    int w = threadIdx.x >> 6, lane = threadIdx.x & 63;
    int idx = blockIdx.x * 4 + w;          // grid exact: 20000 waves
    int slot = (idx >= N_NODES) ? 1 : 0;
    int n = idx - slot * N_NODES;
    int deg = cnt[idx];
    int start = idx * CAP;

    float4 ai4 = *(const float4*)&ai[n * 4];
    float4 aj4n = *(const float4*)&aj[n * 4];
    float ain[4] = {ai4.x, ai4.y, ai4.z, ai4.w};
    float ajn[4] = {aj4n.x, aj4n.y, aj4n.z, aj4n.w};
    int hh = lane >> 4;
    float acc;

    if (deg <= 63) {
        bool act = (lane <= deg);          // lane==deg is the self-loop
        int d = (lane < deg) ? (int)bucket[start + lane] : n;
        float4 a4 = act ? *(const float4*)&aj[d * 4] : make_float4(0.f, 0.f, 0.f, 0.f);
        float ajv[4] = {a4.x, a4.y, a4.z, a4.w};
        float eh[4];
#pragma unroll
        for (int h = 0; h < 4; ++h) {
            float a = ain[h] + ajv[h];
            a = (a < 0.0f) ? 0.2f * a : a;
            eh[h] = act ? fexp(a) : 0.0f;  // no max-shift needed (bounds)
        }
        float sh[4];
#pragma unroll
        for (int h = 0; h < 4; ++h) sh[h] = wsum(eh[h]);
#pragma unroll
        for (int h = 0; h < 4; ++h)
            wlds[w][lane * 4 + h] = eh[h] * (0.25f / (sh[h] + 1e-16f));
        dlds[w][lane] = d;
        // gather, unrolled x8 with independent accumulators (8 loads in flight)
        int m = deg + 1;
        float s0 = 0.f, s1 = 0.f, s2 = 0.f, s3 = 0.f;
        float s4 = 0.f, s5 = 0.f, s6 = 0.f, s7 = 0.f;
        int e = 0;
        for (; e + 8 <= m; e += 8) {
            int d0 = dlds[w][e],     d1 = dlds[w][e + 1];
            int d2 = dlds[w][e + 2], d3 = dlds[w][e + 3];
            int d4 = dlds[w][e + 4], d5 = dlds[w][e + 5];
            int d6 = dlds[w][e + 6], d7 = dlds[w][e + 7];
            float w0 = wlds[w][(e + 0) * 4 + hh], w1 = wlds[w][(e + 1) * 4 + hh];
            float w2 = wlds[w][(e + 2) * 4 + hh], w3 = wlds[w][(e + 3) * 4 + hh];
            float w4 = wlds[w][(e + 4) * 4 + hh], w5 = wlds[w][(e + 5) * 4 + hh];
            float w6 = wlds[w][(e + 6) * 4 + hh], w7 = wlds[w][(e + 7) * 4 + hh];
            s0 = fmaf(w0, xt[d0 * 64 + lane], s0);
            s1 = fmaf(w1, xt[d1 * 64 + lane], s1);
            s2 = fmaf(w2, xt[d2 * 64 + lane], s2);
            s3 = fmaf(w3, xt[d3 * 64 + lane], s3);
            s4 = fmaf(w4, xt[d4 * 64 + lane], s4);
            s5 = fmaf(w5, xt[d5 * 64 + lane], s5);
            s6 = fmaf(w6, xt[d6 * 64 + lane], s6);
            s7 = fmaf(w7, xt[d7 * 64 + lane], s7);
        }
        for (; e + 4 <= m; e += 4) {
            int d0 = dlds[w][e],     d1 = dlds[w][e + 1];
            int d2 = dlds[w][e + 2], d3 = dlds[w][e + 3];
            float w0 = wlds[w][(e + 0) * 4 + hh], w1 = wlds[w][(e + 1) * 4 + hh];
            float w2 = wlds[w][(e + 2) * 4 + hh], w3 = wlds[w][(e + 3) * 4 + hh];
            s0 = fmaf(w0, xt[d0 * 64 + lane], s0);
            s1 = fmaf(w1, xt[d1 * 64 + lane], s1);
            s2 = fmaf(w2, xt[d2 * 64 + lane], s2);
            s3 = fmaf(w3, xt[d3 * 64 + lane], s3);
        }
        for (; e < m; ++e)
            s0 = fmaf(wlds[w][e * 4 + hh], xt[dlds[w][e] * 64 + lane], s0);
        acc = ((s0 + s1) + (s2 + s3)) + ((s4 + s5) + (s6 + s7));
    } else {
        // slow path (rare): strided over bucket + overflow scan, max-shifted
        int bdeg = (deg < CAP) ? deg : CAP;
        int tov = (deg > CAP) ? *ovf_cnt : 0;
        float mh[4];
#pragma unroll
        for (int h = 0; h < 4; ++h) {
            float a = ain[h] + ajn[h];
            mh[h] = (a < 0.0f) ? 0.2f * a : a;
        }
        for (int e = lane; e < bdeg; e += 64) {
            int d = bucket[start + e];
#pragma unroll
            for (int h = 0; h < 4; ++h) {
                float a = ain[h] + aj[d * 4 + h];
                a = (a < 0.0f) ? 0.2f * a : a;
                mh[h] = fmaxf(mh[h], a);
            }
        }
        for (int k = lane; k < tov; k += 64) {
            unsigned pe = ovf[k];
            if ((int)(pe >> 28) == slot && (int)((pe >> 14) & 0x3FFFu) == n) {
                int d = pe & 0x3FFFu;
#pragma unroll
                for (int h = 0; h < 4; ++h) {
                    float a = ain[h] + aj[d * 4 + h];
                    a = (a < 0.0f) ? 0.2f * a : a;
                    mh[h] = fmaxf(mh[h], a);
                }
            }
        }
#pragma unroll
        for (int h = 0; h < 4; ++h) mh[h] = wmax(mh[h]);
        float sh[4] = {0.f, 0.f, 0.f, 0.f};
        if (lane == 0) {
#pragma unroll
            for (int h = 0; h < 4; ++h) {
                float a = ain[h] + ajn[h];
                a = (a < 0.0f) ? 0.2f * a : a;
                sh[h] = fexp(a - mh[h]);
            }
        }
        for (int e = lane; e < bdeg; e += 64) {
            int d = bucket[start + e];
#pragma unroll
            for (int h = 0; h < 4; ++h) {
                float a = ain[h] + aj[d * 4 + h];
                a = (a < 0.0f) ? 0.2f * a : a;
                sh[h] += fexp(a - mh[h]);
            }
        }
        for (int k = lane; k < tov; k += 64) {
            unsigned pe = ovf[k];
            if ((int)(pe >> 28) == slot && (int)((pe >> 14) & 0x3FFFu) == n) {
                int d = pe & 0x3FFFu;
#pragma unroll
                for (int h = 0; h < 4; ++h) {
                    float a = ain[h] + aj[d * 4 + h];
                    a = (a < 0.0f) ? 0.2f * a : a;
                    sh[h] += fexp(a - mh[h]);
                }
            }
        }
#pragma unroll
        for (int h = 0; h < 4; ++h) sh[h] = wsum(sh[h]);
        float scale[4];
#pragma unroll
        for (int h = 0; h < 4; ++h) scale[h] = 0.25f / (sh[h] + 1e-16f);
        float aih = ain[hh], mhh = mh[hh], sch = scale[hh];
        float aself = aih + ajn[hh];
        aself = (aself < 0.0f) ? 0.2f * aself : aself;
        acc = fexp(aself - mhh) * sch * xt[n * 64 + lane];
        for (int e = 0; e < bdeg; ++e) {
            int d = bucket[start + e];
            float a = aih + aj[d * 4 + hh];
            a = (a < 0.0f) ? 0.2f * a : a;
            acc = fmaf(fexp(a - mhh) * sch, xt[d * 64 + lane], acc);
        }
        for (int k = 0; k < tov; ++k) {
            unsigned pe = ovf[k];
            if ((int)(pe >> 28) == slot && (int)((pe >> 14) & 0x3FFFu) == n) {
                int d = pe & 0x3FFFu;
                float a = aih + aj[d * 4 + hh];
                a = (a < 0.0f) ? 0.2f * a : a;
                acc = fmaf(fexp(a - mhh) * sch, xt[d * 64 + lane], acc);
            }
        }
    }
    acc += __shfl_xor(acc, 16, 64);        // head mean (x0.25 in scale)
    acc += __shfl_xor(acc, 32, 64);
    if (lane < 16) sup_t[lane * 20000 + idx] = acc;
}

// ---------- kernel 3: hyperbolic head, 4-wave cooperative (verified R7/R13) ----------
__global__ __launch_bounds__(256) void final_stage(const float* __restrict__ sup_t,
                                                   const float* __restrict__ wf1t,
                                                   const float* __restrict__ wf2t,
                                                   const float* __restrict__ hb1f,
                                                   const float* __restrict__ hb2f,
                                                   const float* __restrict__ hbn2,
                                                   const int* __restrict__ flag,
                                                   void* __restrict__ outv) {
    __shared__ float Z[65 * 64];           // z2s [c*64+node] then T [o*65+node]
    __shared__ float pA[2][4][64];
    __shared__ float pB[2][4][64];
    int w = threadIdx.x >> 6, lane = threadIdx.x & 63;
    int base = blockIdx.x * 64;            // grid: 313 blocks
    int nd = base + lane;
    bool valid = (nd < 2 * N_NODES);
    int isbf = *flag;
    float y2a = hbn2[0], y2b = hbn2[1];
    int ob = w * 16;                       // owned output base

    float v[16];
#pragma unroll
    for (int c = 0; c < 16; ++c) v[c] = valid ? sup_t[c * 20000 + nd] : 0.0f;
    float n2 = 0.f;
#pragma unroll
    for (int c = 0; c < 16; ++c) n2 = fmaf(v[c], v[c], n2);
    float n = fmaxf(sqrtf(n2), EPS);
    float th0 = ftanh_pos(SQRT_C * n);
    float s0 = th0 / (SQRT_C * n);
    float x0n = th0 / SQRT_C;
    if (x0n > MAXNORM) { s0 *= MAXNORM / x0n; x0n = MAXNORM; }
#pragma unroll
    for (int c = 0; c < 16; ++c) v[c] *= s0;

    float a1[16];
#pragma unroll
    for (int oj = 0; oj < 16; ++oj) a1[oj] = 0.f;
#pragma unroll
    for (int c = 0; c < 16; ++c) {
        float vc = v[c];
#pragma unroll
        for (int oj = 0; oj < 16; ++oj)
            a1[oj] = fmaf(wf1t[c * 64 + ob + oj], vc, a1[oj]);
    }
    float pn = 0.f, ph = 0.f;
#pragma unroll
    for (int oj = 0; oj < 16; ++oj) {
        pn = fmaf(a1[oj], a1[oj], pn);
        ph = fmaf(a1[oj], hb1f[ob + oj], ph);
    }
    pA[0][w][lane] = pn; pA[1][w][lane] = ph;
    __syncthreads();
    float mxn2 = pA[0][0][lane] + pA[0][1][lane] + pA[0][2][lane] + pA[0][3][lane];
    float mxhb = pA[1][0][lane] + pA[1][1][lane] + pA[1][2][lane] + pA[1][3][lane];

    float z2n;
    {
        float xn = fmaxf(x0n, EPS);
        float mxn = fmaxf(sqrtf(mxn2), EPS);
        float t = fminf(SQRT_C * xn, 1.0f - 1e-7f);
        float th = ftanh_pos(mxn / xn * fatanh01(t));
        float rs = th / (mxn * SQRT_C);
        float rn = th / SQRT_C;
        if (mxn2 == 0.0f) { rs = 0.f; rn = 0.f; }      // all(mx==0) guard
        if (rn > MAXNORM) { rs *= MAXNORM / rn; rn = MAXNORM; }
        float xy = rs * mxhb;
        float x2 = rn * rn;
        float A = 1.0f + 2.0f * CC * xy + CC * y2a;
        float B = 1.0f - CC * x2;
        float rden = 1.0f / fmaxf(1.0f + 2.0f * CC * xy + CC * CC * x2 * y2a, EPS);
        float pz = 0.f;
#pragma unroll
        for (int oj = 0; oj < 16; ++oj) {
            float z = (A * rs * a1[oj] + B * hb1f[ob + oj]) * rden;
            a1[oj] = z;
            pz = fmaf(z, z, pz);
        }
        pB[0][w][lane] = pz;
        __syncthreads();
        float zn2 = pB[0][0][lane] + pB[0][1][lane] + pB[0][2][lane] + pB[0][3][lane];
        float zn = fmaxf(sqrtf(zn2), EPS);
        float sc = (zn > MAXNORM) ? MAXNORM / zn : 1.0f;
        float z1n = fminf(zn, MAXNORM);
        float lg = fatanh01(fminf(SQRT_C * z1n, 1.0f - 1e-7f)) / (SQRT_C * z1n) * sc;
        float pu = 0.f;
#pragma unroll
        for (int oj = 0; oj < 16; ++oj) {
            float u = lg * a1[oj];
            u = u / (1.0f + __expf(-u));
            a1[oj] = u;
            pu = fmaf(u, u, pu);
        }
        pA[0][w][lane] = pu;
        __syncthreads();
        float un2 = pA[0][0][lane] + pA[0][1][lane] + pA[0][2][lane] + pA[0][3][lane];
        float un = fmaxf(sqrtf(un2), EPS);
        float th2 = ftanh_pos(SQRT_C * un);
        float s2 = th2 / (SQRT_C * un);
        z2n = th2 / SQRT_C;
        if (z2n > MAXNORM) { s2 *= MAXNORM / z2n; z2n = MAXNORM; }
#pragma unroll
        for (int oj = 0; oj < 16; ++oj) Z[(ob + oj) * 64 + lane] = a1[oj] * s2;
        // HypDropout eval round-trip == identity (no clip possible) -> skip
    }
    __syncthreads();

    float a2[16];
#pragma unroll
    for (int oj = 0; oj < 16; ++oj) a2[oj] = 0.f;
#pragma unroll 4
    for (int c = 0; c < 64; ++c) {
        float zc = Z[c * 64 + lane];
#pragma unroll
        for (int oj = 0; oj < 16; ++oj)
            a2[oj] = fmaf(wf2t[c * 64 + ob + oj], zc, a2[oj]);
    }
    float pn2 = 0.f, ph2 = 0.f;
#pragma unroll
    for (int oj = 0; oj < 16; ++oj) {
        pn2 = fmaf(a2[oj], a2[oj], pn2);
        ph2 = fmaf(a2[oj], hb2f[ob + oj], ph2);
    }
    pB[0][w][lane] = pn2; pB[1][w][lane] = ph2;
    __syncthreads();
    float mxn2b = pB[0][0][lane] + pB[0][1][lane] + pB[0][2][lane] + pB[0][3][lane];
    float mxhb2 = pB[1][0][lane] + pB[1][1][lane] + pB[1][2][lane] + pB[1][3][lane];
    {
        float xn = fmaxf(z2n, EPS);
        float mxn = fmaxf(sqrtf(mxn2b), EPS);
        float t = fminf(SQRT_C * xn, 1.0f - 1e-7f);
        float th = ftanh_pos(mxn / xn * fatanh01(t));
        float rs = th / (mxn * SQRT_C);
        float rn = th / SQRT_C;
        if (mxn2b == 0.0f) { rs = 0.f; rn = 0.f; }
        if (rn > MAXNORM) { rs *= MAXNORM / rn; rn = MAXNORM; }
        float xy = rs * mxhb2;
        float x2 = rn * rn;
        float A = 1.0f + 2.0f * CC * xy + CC * y2b;
        float B = 1.0f - CC * x2;
        float rden = 1.0f / fmaxf(1.0f + 2.0f * CC * xy + CC * CC * x2 * y2b, EPS);
        float pz = 0.f;
#pragma unroll
        for (int oj = 0; oj < 16; ++oj) {
            float z = (A * rs * a2[oj] + B * hb2f[ob + oj]) * rden;
            a2[oj] = z;
            pz = fmaf(z, z, pz);
        }
        pA[0][w][lane] = pz;
        __syncthreads();
        float zn2 = pA[0][0][lane] + pA[0][1][lane] + pA[0][2][lane] + pA[0][3][lane];
        float zn = fmaxf(sqrtf(zn2), EPS);
        float s4 = (zn > MAXNORM) ? MAXNORM / zn : 1.0f;
#pragma unroll
        for (int oj = 0; oj < 16; ++oj) Z[(ob + oj) * 65 + lane] = a2[oj] * s4;
    }
    __syncthreads();

#pragma unroll 1
    for (int k = 0; k < 16; ++k) {
        int nl = w * 16 + k;
        int ng = base + nl;
        if (ng >= 2 * N_NODES) break;
        float val = Z[lane * 65 + nl];
        if (isbf) ((__hip_bfloat16*)outv)[ng * 64 + lane] = __float2bfloat16(val);
        else      ((float*)outv)[ng * 64 + lane] = val;
    }
}

extern "C" void kernel_launch(void* const* d_in, const int* in_sizes, int n_in,
                              void* d_out, int out_size, void* d_ws, size_t ws_size,
                              hipStream_t stream) {
    // setup_inputs order: history_graphs(0, unused), edge_index(1), emb(2),
    //                     att_i(3), att_j(4), w1(5), b1(6), w2(7), b2(8)
    const int* ei = (const int*)d_in[1];
    const void* emb   = d_in[2];
    const void* att_i = d_in[3];
    const void* att_j = d_in[4];
    const void* w1 = d_in[5];
    const void* b1 = d_in[6];
    const void* w2 = d_in[7];
    const void* b2 = d_in[8];

    // workspace layout (float words), ~9.4 MB total. NO OVERLAPS (R11-verified):
    //   bucket [20000][96] u16 = 960000 float words: 1060032 .. 2020032
    float* ws = (float*)d_ws;
    float* xt    = ws;                                // [10000][64]: 0..640000
    float* ai    = ws + 640000;                       // [10000][4]
    float* aj    = ws + 680000;                       // [10000][4]
    float* sup_t = ws + 720000;                       // [16][20000]: ..1040000
    int* cnt     = (int*)(ws + 1040000);              // [2][10000]: ..1060000
    int* ovf_cnt = (int*)(ws + 1060000);              // 1 int (memset covers it)
    unsigned short* bucket = (unsigned short*)(ws + 1060032); // ..2020032
    unsigned* ovf = (unsigned*)(ws + 2020032);        // [320000]: ..2340032
    int* flag     = (int*)(ws + 2340032);
    float* wf1t = ws + 2340064;                       // [16][64]: ..2341088
    float* wf2t = ws + 2341088;                       // [64][64]: ..2345184
    float* hb1f = ws + 2345184;                       // [64]
    float* hb2f = ws + 2345248;                       // [64]
    float* hbn2 = ws + 2345312;                       // [2]

    // zero cnt[20000] + ovf_cnt in one 80 KB fill
    hipMemsetAsync((void*)cnt, 0, (2 * N_NODES + 8) * sizeof(int), stream);
    hipLaunchKernelGGL(pre_scatter, dim3(2814), dim3(256), 0, stream,
                       emb, att_i, att_j, w1, b1, w2, b2, ei,
                       xt, ai, aj, cnt, bucket, ovf_cnt, ovf, flag,
                       wf1t, wf2t, hb1f, hb2f, hbn2);
    hipLaunchKernelGGL(node_agg, dim3(5000), dim3(256), 0, stream,
                       cnt, bucket, ovf_cnt, ovf, ai, aj, xt, sup_t);
    hipLaunchKernelGGL(final_stage, dim3(313), dim3(256), 0, stream,
                       sup_t, wf1t, wf2t, hb1f, hb2f, hbn2, flag, d_out);
}